// Round 1
// baseline (553.769 us; speedup 1.0000x reference)
//
#include <hip/hip_runtime.h>
#include <stdint.h>

// ---------------------------------------------------------------------------
// GPT-2 attention block: qkv = X@W + b; causal MHA; outputs attn_out + present
// B=4 S=2048 D=1024 H=16 Dh=64.  bf16 MFMA path (threshold ~7.5e-2 admits it).
// ---------------------------------------------------------------------------

#define B_SZ    4
#define S_LEN   2048
#define D_MODEL 1024
#define N3      3072
#define H_NUM   16
#define DH      64
#define M_TOT   8192   // B*S

typedef __attribute__((ext_vector_type(8))) short short8;   // 8 bf16 (4 VGPRs)
typedef __attribute__((ext_vector_type(4))) float f32x4;    // MFMA C/D

__device__ __forceinline__ unsigned short f2b(float f) {
  union { float f; unsigned int u; } x;
  x.f = f;
  unsigned int u = x.u;
  u += 0x7fffu + ((u >> 16) & 1u);   // round-to-nearest-even
  return (unsigned short)(u >> 16);
}

// async global->LDS, 16B per lane. lds ptr must be wave-uniform (lane*16 added by HW).
__device__ __forceinline__ void async16(const void* g, void* l) {
  __builtin_amdgcn_global_load_lds((const __attribute__((address_space(1))) void*)g,
                                   (__attribute__((address_space(3))) void*)l,
                                   16, 0, 0);
}

// ---------------- kernel 1: hidden_states fp32 -> bf16 ---------------------
__global__ void k_convert_x(const float* __restrict__ X, unsigned short* __restrict__ Xb) {
  const int i = (blockIdx.x * 256 + threadIdx.x) * 4;
  const float4 v = *(const float4*)(X + i);
  ushort4 o;
  o.x = f2b(v.x); o.y = f2b(v.y); o.z = f2b(v.z); o.w = f2b(v.w);
  *(ushort4*)(Xb + i) = o;
}

// ---------------- kernel 2: W [D,3D] fp32 -> W^T [3D,D] bf16 ----------------
__global__ void k_wt(const float* __restrict__ W, unsigned short* __restrict__ Wt) {
  __shared__ float tile[32][33];
  const int n0 = blockIdx.x * 32, k0 = blockIdx.y * 32;
  const int tx = threadIdx.x, ty = threadIdx.y;   // 32 x 8
  for (int i = 0; i < 32; i += 8)
    tile[ty + i][tx] = W[(size_t)(k0 + ty + i) * N3 + n0 + tx];
  __syncthreads();
  for (int i = 0; i < 32; i += 8)
    Wt[(size_t)(n0 + ty + i) * D_MODEL + k0 + tx] = f2b(tile[tx][ty + i]);
}

// ---------------- kernel 3: QKV GEMM (128x128 tile, BK=32) ------------------
// C[m,n] = sum_k Xb[m,k]*Wt[n,k] + bias[n];  epilogue scatters q/k/v.
__global__ __launch_bounds__(256) void k_gemm_qkv(
    const unsigned short* __restrict__ Xb, const unsigned short* __restrict__ Wt,
    const float* __restrict__ bias,
    unsigned short* __restrict__ Qb, unsigned short* __restrict__ Kb,
    unsigned short* __restrict__ Vt,
    float* __restrict__ presK, float* __restrict__ presV) {
  __shared__ __align__(16) unsigned short As[128 * 32];
  __shared__ __align__(16) unsigned short Bs[128 * 32];
  const int t = threadIdx.x;
  const int lane = t & 63, wave = t >> 6;
  const int g = lane >> 4, c = lane & 15;
  const int m0 = blockIdx.y * 128, n0 = blockIdx.x * 128;
  const int wm = (wave >> 1) * 64, wn = (wave & 1) * 64;

  const f32x4 zero = {0.f, 0.f, 0.f, 0.f};
  f32x4 acc[4][4];
  for (int i = 0; i < 4; ++i)
    for (int j = 0; j < 4; ++j) acc[i][j] = zero;

  const int row_a = t >> 2;          // 0..63
  const int col_a = (t & 3) * 8;     // bf16 elems
  const unsigned short* gA = Xb + (size_t)(m0 + row_a) * D_MODEL + col_a;
  const unsigned short* gB = Wt + (size_t)(n0 + row_a) * D_MODEL + col_a;
  const int wbase = wave * 1024;     // wave-uniform LDS byte base (64 lanes * 16B)

  for (int k0 = 0; k0 < D_MODEL; k0 += 32) {
    __syncthreads();  // previous iter's LDS reads done before overwrite
    async16(gA + k0,                (char*)As + wbase);
    async16(gA + k0 + 64 * D_MODEL, (char*)As + 4096 + wbase);
    async16(gB + k0,                (char*)Bs + wbase);
    async16(gB + k0 + 64 * D_MODEL, (char*)Bs + 4096 + wbase);
    __syncthreads();  // compiler drains vmcnt before barrier -> staging visible

    short8 af[4], bf[4];
    for (int mi = 0; mi < 4; ++mi)
      af[mi] = *(const short8*)(As + (wm + mi * 16 + c) * 32 + g * 8);
    for (int ni = 0; ni < 4; ++ni)
      bf[ni] = *(const short8*)(Bs + (wn + ni * 16 + c) * 32 + g * 8);
    for (int mi = 0; mi < 4; ++mi)
      for (int ni = 0; ni < 4; ++ni)
        acc[mi][ni] = __builtin_amdgcn_mfma_f32_16x16x32_bf16(af[mi], bf[ni], acc[mi][ni], 0, 0, 0);
  }

  // epilogue: bias + scatter.  C/D layout: col=lane&15, row=(lane>>4)*4+reg.
  for (int ni = 0; ni < 4; ++ni) {
    const int n = n0 + wn + ni * 16 + c;
    const float bv = bias[n];
    const int sec = n >> 10;            // 0=q 1=k 2=v
    const int d = n & 1023;
    const int h = d >> 6, dh = d & 63;
    for (int mi = 0; mi < 4; ++mi) {
      for (int r = 0; r < 4; ++r) {
        const int m = m0 + wm + mi * 16 + g * 4 + r;
        const int b = m >> 11, s = m & 2047;
        const float val = acc[mi][ni][r] + bv;
        const size_t hidx = ((size_t)((b * H_NUM + h) * S_LEN + s)) * DH + dh;
        if (sec == 0) {
          Qb[hidx] = f2b(val);
        } else if (sec == 1) {
          presK[hidx] = val;
          Kb[hidx] = f2b(val);
        } else {
          presV[hidx] = val;
          Vt[((size_t)((b * H_NUM + h) * DH + dh)) * S_LEN + s] = f2b(val);
        }
      }
    }
  }
}

// ---------------- kernel 4: causal flash attention --------------------------
// grid (16 q-tiles, 64 bh); 4 independent waves x 32 q-rows; k-tiles of 64.
__global__ __launch_bounds__(256) void k_flash(
    const unsigned short* __restrict__ Qb, const unsigned short* __restrict__ Kb,
    const unsigned short* __restrict__ Vt, const float* __restrict__ mask,
    float* __restrict__ out) {
  __shared__ __align__(16) unsigned short Ps[4][32 * 72];  // per-wave P slab, swizzled
  const int lane = threadIdx.x & 63, wave = threadIdx.x >> 6;
  const int g = lane >> 4, c = lane & 15;
  const int bh = blockIdx.y;
  const int b = bh >> 4, h = bh & 15;
  const int qbase = blockIdx.x * 128 + wave * 32;

  // Q fragments (A-layout: m=lane&15, k=(lane>>4)*8+j)
  short8 aq[2][2];
  const size_t qoff = ((size_t)bh * S_LEN + qbase) * DH;
  for (int mi = 0; mi < 2; ++mi)
    for (int kc = 0; kc < 2; ++kc)
      aq[mi][kc] = *(const short8*)(Qb + qoff + (size_t)(mi * 16 + c) * DH + kc * 32 + g * 8);

  const f32x4 zero = {0.f, 0.f, 0.f, 0.f};
  float m_i[2][4], l_i[2][4];
  f32x4 o_acc[2][4];
  for (int mi = 0; mi < 2; ++mi)
    for (int r = 0; r < 4; ++r) { m_i[mi][r] = -1e30f; l_i[mi][r] = 0.f; }
  for (int mi = 0; mi < 2; ++mi)
    for (int u = 0; u < 4; ++u) o_acc[mi][u] = zero;

  unsigned short* ps = &Ps[wave][0];

  for (int kb = 0; kb < qbase + 32; kb += 64) {
    // ---- S = Q K^T  (16 MFMA) ----
    f32x4 sc[2][4];
    for (int mi = 0; mi < 2; ++mi)
      for (int ks = 0; ks < 4; ++ks) sc[mi][ks] = zero;
    for (int ks = 0; ks < 4; ++ks) {
      const size_t koff = ((size_t)bh * S_LEN + kb + ks * 16 + c) * DH;
      for (int kc = 0; kc < 2; ++kc) {
        const short8 bk = *(const short8*)(Kb + koff + kc * 32 + g * 8);
        for (int mi = 0; mi < 2; ++mi)
          sc[mi][ks] = __builtin_amdgcn_mfma_f32_16x16x32_bf16(aq[mi][kc], bk, sc[mi][ks], 0, 0, 0);
      }
    }
    // ---- scale, causal, attention_mask ----
    float am[4];
    for (int ks = 0; ks < 4; ++ks)
      am[ks] = (1.0f - mask[b * S_LEN + kb + ks * 16 + c]) * -10000.0f;
    for (int mi = 0; mi < 2; ++mi)
      for (int r = 0; r < 4; ++r) {
        const int qrow = qbase + mi * 16 + g * 4 + r;
        for (int ks = 0; ks < 4; ++ks) {
          const int kcol = kb + ks * 16 + c;
          float v = sc[mi][ks][r] * 0.125f;        // 1/sqrt(64)
          if (kcol > qrow) v = -10000.0f;          // causal (matches ref semantics)
          sc[mi][ks][r] = v + am[ks];
        }
      }
    // ---- online softmax (row = 16 lanes sharing l>>4; xor-shuffle reduce) ----
    for (int mi = 0; mi < 2; ++mi)
      for (int r = 0; r < 4; ++r) {
        float mx = sc[mi][0][r];
        for (int ks = 1; ks < 4; ++ks) mx = fmaxf(mx, sc[mi][ks][r]);
        for (int off = 1; off < 16; off <<= 1) mx = fmaxf(mx, __shfl_xor(mx, off));
        const float mnew = fmaxf(m_i[mi][r], mx);
        const float alpha = __expf(m_i[mi][r] - mnew);
        m_i[mi][r] = mnew;
        float rs = 0.f;
        for (int ks = 0; ks < 4; ++ks) {
          const float p = __expf(sc[mi][ks][r] - mnew);
          sc[mi][ks][r] = p;
          rs += p;
        }
        for (int off = 1; off < 16; off <<= 1) rs += __shfl_xor(rs, off);
        l_i[mi][r] = l_i[mi][r] * alpha + rs;
        for (int u = 0; u < 4; ++u) o_acc[mi][u][r] *= alpha;
      }
    // ---- P: C-layout -> A-layout via swizzled LDS (stride 72, chunk-XOR) ----
    for (int mi = 0; mi < 2; ++mi)
      for (int r = 0; r < 4; ++r) {
        const int ql = mi * 16 + g * 4 + r;
        const int sw = ((ql >> 2) & 3) * 8;
        for (int ks = 0; ks < 4; ++ks) {
          const int kk = ks * 16 + c;
          ps[ql * 72 + (kk ^ sw)] = f2b(sc[mi][ks][r]);
        }
      }
    short8 ap[2][2];
    for (int mi = 0; mi < 2; ++mi) {
      const int ql = mi * 16 + c;
      const int sw = ((ql >> 2) & 3) * 8;
      for (int kc = 0; kc < 2; ++kc) {
        const int kk = kc * 32 + g * 8;
        ap[mi][kc] = *(const short8*)(ps + ql * 72 + (kk ^ sw));
      }
    }
    // ---- O += P V  (V^T fragments straight from global; 16 MFMA) ----
    for (int u = 0; u < 4; ++u)
      for (int kc = 0; kc < 2; ++kc) {
        const short8 bv = *(const short8*)(Vt + ((size_t)bh * DH + u * 16 + c) * S_LEN
                                           + kb + kc * 32 + g * 8);
        for (int mi = 0; mi < 2; ++mi)
          o_acc[mi][u] = __builtin_amdgcn_mfma_f32_16x16x32_bf16(ap[mi][kc], bv, o_acc[mi][u], 0, 0, 0);
      }
  }

  // ---- normalize + merge heads ----
  for (int mi = 0; mi < 2; ++mi)
    for (int r = 0; r < 4; ++r) {
      const float inv = 1.0f / l_i[mi][r];
      const int srow = qbase + mi * 16 + g * 4 + r;
      float* orow = out + ((size_t)(b * S_LEN + srow)) * D_MODEL + h * DH;
      for (int u = 0; u < 4; ++u)
        orow[u * 16 + c] = o_acc[mi][u][r] * inv;
    }
}

// ---------------------------------------------------------------------------
extern "C" void kernel_launch(void* const* d_in, const int* in_sizes, int n_in,
                              void* d_out, int out_size, void* d_ws, size_t ws_size,
                              hipStream_t stream) {
  const float* X    = (const float*)d_in[0];   // [4,2048,1024]
  const float* mask = (const float*)d_in[1];   // [4,2048]
  const float* W    = (const float*)d_in[2];   // [1024,3072]
  const float* bias = (const float*)d_in[3];   // [3072]

  float* out   = (float*)d_out;                         // attn_output [4,2048,1024]
  float* presK = out + (size_t)M_TOT * D_MODEL;         // present[0]  [4,16,2048,64]
  float* presV = presK + (size_t)M_TOT * D_MODEL;       // present[1]

  char* ws = (char*)d_ws;
  unsigned short* Xb = (unsigned short*)(ws);                    // 16 MB  X bf16 [8192,1024]
  unsigned short* Wt = (unsigned short*)(ws + 16777216);         //  6 MB  W^T bf16 [3072,1024]
  unsigned short* Qb = (unsigned short*)(ws + 23068672);         // 16 MB  Q bf16 [bh,2048,64]
  unsigned short* Kb = (unsigned short*)(ws + 39845888);         // 16 MB  K bf16 [bh,2048,64]
  unsigned short* Vt = (unsigned short*)(ws + 56623104);         // 16 MB  V^T bf16 [bh,64,2048]

  k_convert_x<<<dim3(8192), dim3(256), 0, stream>>>(X, Xb);
  k_wt<<<dim3(96, 32), dim3(32, 8), 0, stream>>>(W, Wt);
  k_gemm_qkv<<<dim3(24, 64), dim3(256), 0, stream>>>(Xb, Wt, bias, Qb, Kb, Vt, presK, presV);
  k_flash<<<dim3(16, 64), dim3(256), 0, stream>>>(Qb, Kb, Vt, mask, out);
}

// Round 3
// 366.387 us; speedup vs baseline: 1.5114x; 1.5114x over previous
//
#include <hip/hip_runtime.h>
#include <stdint.h>

// ---------------------------------------------------------------------------
// GPT-2 attention block: qkv = X@W + b; causal MHA; outputs attn_out + present
// B=4 S=2048 D=1024 H=16 Dh=64.  bf16 MFMA path.
// R3: fix R2's half-staged K/V LDS tile (256 thr x 16B = 4KB but tile is 8KB
//     -> NaN from uninitialized LDS). Now 2 halves x 16B per thread.
// ---------------------------------------------------------------------------

#define B_SZ    4
#define S_LEN   2048
#define D_MODEL 1024
#define N3      3072
#define H_NUM   16
#define DH      64
#define M_TOT   8192   // B*S

typedef __attribute__((ext_vector_type(8))) short short8;   // 8 bf16 (4 VGPRs)
typedef __attribute__((ext_vector_type(4))) float f32x4;    // MFMA C/D

__device__ __forceinline__ unsigned short f2b(float f) {
  union { float f; unsigned int u; } x;
  x.f = f;
  unsigned int u = x.u;
  u += 0x7fffu + ((u >> 16) & 1u);   // round-to-nearest-even
  return (unsigned short)(u >> 16);
}

// async global->LDS, 16B per lane (GEMM staging only; layout must be unpadded).
__device__ __forceinline__ void async16(const void* g, void* l) {
  __builtin_amdgcn_global_load_lds((const __attribute__((address_space(1))) void*)g,
                                   (__attribute__((address_space(3))) void*)l,
                                   16, 0, 0);
}

// ---------------- kernel 1: hidden_states fp32 -> bf16 ---------------------
__global__ void k_convert_x(const float* __restrict__ X, unsigned short* __restrict__ Xb) {
  const int i = (blockIdx.x * 256 + threadIdx.x) * 4;
  const float4 v = *(const float4*)(X + i);
  ushort4 o;
  o.x = f2b(v.x); o.y = f2b(v.y); o.z = f2b(v.z); o.w = f2b(v.w);
  *(ushort4*)(Xb + i) = o;
}

// ---------------- kernel 2: W [D,3D] fp32 -> W^T [3D,D] bf16 ----------------
__global__ void k_wt(const float* __restrict__ W, unsigned short* __restrict__ Wt) {
  __shared__ float tile[32][33];
  const int n0 = blockIdx.x * 32, k0 = blockIdx.y * 32;
  const int tx = threadIdx.x, ty = threadIdx.y;   // 32 x 8
  for (int i = 0; i < 32; i += 8)
    tile[ty + i][tx] = W[(size_t)(k0 + ty + i) * N3 + n0 + tx];
  __syncthreads();
  for (int i = 0; i < 32; i += 8)
    Wt[(size_t)(n0 + ty + i) * D_MODEL + k0 + tx] = f2b(tile[tx][ty + i]);
}

// ---------------- kernel 3: QKV GEMM (128x128 tile, BK=32) ------------------
__global__ __launch_bounds__(256) void k_gemm_qkv(
    const unsigned short* __restrict__ Xb, const unsigned short* __restrict__ Wt,
    const float* __restrict__ bias,
    unsigned short* __restrict__ Qb, unsigned short* __restrict__ Kb,
    unsigned short* __restrict__ Vb,
    float* __restrict__ presK, float* __restrict__ presV) {
  __shared__ __align__(16) unsigned short As[128 * 32];
  __shared__ __align__(16) unsigned short Bs[128 * 32];
  const int t = threadIdx.x;
  const int lane = t & 63, wave = t >> 6;
  const int g = lane >> 4, c = lane & 15;
  const int m0 = blockIdx.y * 128, n0 = blockIdx.x * 128;
  const int wm = (wave >> 1) * 64, wn = (wave & 1) * 64;

  const f32x4 zero = {0.f, 0.f, 0.f, 0.f};
  f32x4 acc[4][4];
  for (int i = 0; i < 4; ++i)
    for (int j = 0; j < 4; ++j) acc[i][j] = zero;

  const int row_a = t >> 2;          // 0..63
  const int col_a = (t & 3) * 8;     // bf16 elems
  const unsigned short* gA = Xb + (size_t)(m0 + row_a) * D_MODEL + col_a;
  const unsigned short* gB = Wt + (size_t)(n0 + row_a) * D_MODEL + col_a;
  const int wbase = wave * 1024;     // wave-uniform LDS byte base (64 lanes * 16B)

  for (int k0 = 0; k0 < D_MODEL; k0 += 32) {
    __syncthreads();
    async16(gA + k0,                (char*)As + wbase);
    async16(gA + k0 + 64 * D_MODEL, (char*)As + 4096 + wbase);
    async16(gB + k0,                (char*)Bs + wbase);
    async16(gB + k0 + 64 * D_MODEL, (char*)Bs + 4096 + wbase);
    __syncthreads();

    short8 af[4], bf[4];
    for (int mi = 0; mi < 4; ++mi)
      af[mi] = *(const short8*)(As + (wm + mi * 16 + c) * 32 + g * 8);
    for (int ni = 0; ni < 4; ++ni)
      bf[ni] = *(const short8*)(Bs + (wn + ni * 16 + c) * 32 + g * 8);
    for (int mi = 0; mi < 4; ++mi)
      for (int ni = 0; ni < 4; ++ni)
        acc[mi][ni] = __builtin_amdgcn_mfma_f32_16x16x32_bf16(af[mi], bf[ni], acc[mi][ni], 0, 0, 0);
  }

  // epilogue: bias + scatter.  C/D layout: col=lane&15, row=(lane>>4)*4+reg.
  for (int ni = 0; ni < 4; ++ni) {
    const int n = n0 + wn + ni * 16 + c;
    const float bv = bias[n];
    const int sec = n >> 10;            // 0=q 1=k 2=v
    const int d = n & 1023;
    const int h = d >> 6, dh = d & 63;
    for (int mi = 0; mi < 4; ++mi) {
      for (int r = 0; r < 4; ++r) {
        const int m = m0 + wm + mi * 16 + g * 4 + r;
        const int b = m >> 11, s = m & 2047;
        const float val = acc[mi][ni][r] + bv;
        const size_t hidx = ((size_t)((b * H_NUM + h) * S_LEN + s)) * DH + dh;
        if (sec == 0) {
          Qb[hidx] = f2b(val);
        } else if (sec == 1) {
          presK[hidx] = val;
          Kb[hidx] = f2b(val);
        } else {
          presV[hidx] = val;
          Vb[hidx] = f2b(val);
        }
      }
    }
  }
}

// ---------------- kernel 4: causal flash attention --------------------------
// grid (8, 64 bh); block handles q-tile pair (x, 15-x) -> constant 34 k-iters.
// K/V tiles staged in LDS (padded stride 72); V transposed during staging.
__global__ __launch_bounds__(256) void k_flash(
    const unsigned short* __restrict__ Qb, const unsigned short* __restrict__ Kb,
    const unsigned short* __restrict__ Vb, const float* __restrict__ mask,
    float* __restrict__ out) {
  __shared__ __align__(16) unsigned short Ks[64 * 72];     // [krow][dh] padded
  __shared__ __align__(16) unsigned short Vs[64 * 72];     // [dh][krow] padded
  __shared__ __align__(16) unsigned short Ps[4][32 * 72];  // per-wave P slab
  const int t = threadIdx.x;
  const int lane = t & 63, wave = t >> 6;
  const int g = lane >> 4, c = lane & 15;
  const int bh = blockIdx.y;
  const int b = bh >> 4, h = bh & 15;
  const int srow_st = t >> 2;          // 0..63
  const int schunk0 = t & 3;           // 0..3 (halves add +4)
  unsigned short* ps = &Ps[wave][0];

  for (int phase = 0; phase < 2; ++phase) {
    const int x = phase == 0 ? (int)blockIdx.x : 15 - (int)blockIdx.x;
    const int qb = x * 128;              // block q-tile base
    const int qbase = qb + wave * 32;    // this wave's q rows

    // Q fragments (A-layout: m=lane&15, k=(lane>>4)*8+j)
    short8 aq[2][2];
    const size_t qoff = ((size_t)bh * S_LEN + qbase) * DH;
    for (int mi = 0; mi < 2; ++mi)
      for (int kc = 0; kc < 2; ++kc)
        aq[mi][kc] = *(const short8*)(Qb + qoff + (size_t)(mi * 16 + c) * DH + kc * 32 + g * 8);

    const f32x4 zero = {0.f, 0.f, 0.f, 0.f};
    float m_i[2][4], l_i[2][4];
    f32x4 o_acc[2][4];
    for (int mi = 0; mi < 2; ++mi)
      for (int r = 0; r < 4; ++r) { m_i[mi][r] = -1e30f; l_i[mi][r] = 0.f; }
    for (int mi = 0; mi < 2; ++mi)
      for (int u = 0; u < 4; ++u) o_acc[mi][u] = zero;

    const int kmax = qb + 128;           // block-uniform bound (mask absorbs extra)
    for (int kb = 0; kb < kmax; kb += 64) {
      __syncthreads();  // previous iteration's LDS reads complete
      // ---- stage K tile [64 krow][64 dh] + V^T tile, FULL 8KB each ----
      for (int half = 0; half < 2; ++half) {
        const int chunk = schunk0 + half * 4;          // 0..7
        const size_t go = ((size_t)bh * S_LEN + kb + srow_st) * DH + chunk * 8;
        const short8 kvv = *(const short8*)(Kb + go);
        *(short8*)(Ks + srow_st * 72 + chunk * 8) = kvv;
        const short8 vvv = *(const short8*)(Vb + go);
        for (int j = 0; j < 8; ++j)
          Vs[(chunk * 8 + j) * 72 + srow_st] = (unsigned short)vvv[j];
      }
      __syncthreads();

      // ---- S = Q K^T (16 MFMA, frags from LDS) ----
      f32x4 sc[2][4];
      for (int mi = 0; mi < 2; ++mi)
        for (int ks = 0; ks < 4; ++ks) sc[mi][ks] = zero;
      for (int ks = 0; ks < 4; ++ks)
        for (int kc = 0; kc < 2; ++kc) {
          const short8 bk = *(const short8*)(Ks + (ks * 16 + c) * 72 + kc * 32 + g * 8);
          for (int mi = 0; mi < 2; ++mi)
            sc[mi][ks] = __builtin_amdgcn_mfma_f32_16x16x32_bf16(aq[mi][kc], bk, sc[mi][ks], 0, 0, 0);
        }

      // ---- scale, causal, attention_mask ----
      float am[4];
      for (int ks = 0; ks < 4; ++ks)
        am[ks] = (1.0f - mask[b * S_LEN + kb + ks * 16 + c]) * -10000.0f;
      for (int mi = 0; mi < 2; ++mi)
        for (int r = 0; r < 4; ++r) {
          const int qrow = qbase + mi * 16 + g * 4 + r;
          for (int ks = 0; ks < 4; ++ks) {
            const int kcol = kb + ks * 16 + c;
            float v = sc[mi][ks][r] * 0.125f;        // 1/sqrt(64)
            if (kcol > qrow) v = -10000.0f;          // causal (ref semantics)
            sc[mi][ks][r] = v + am[ks];
          }
        }

      // ---- online softmax (row = 16 lanes sharing g; xor-shuffle reduce) ----
      for (int mi = 0; mi < 2; ++mi)
        for (int r = 0; r < 4; ++r) {
          float mx = sc[mi][0][r];
          for (int ks = 1; ks < 4; ++ks) mx = fmaxf(mx, sc[mi][ks][r]);
          for (int off = 1; off < 16; off <<= 1) mx = fmaxf(mx, __shfl_xor(mx, off));
          const float mnew = fmaxf(m_i[mi][r], mx);
          const float alpha = __expf(m_i[mi][r] - mnew);
          m_i[mi][r] = mnew;
          float rs = 0.f;
          for (int ks = 0; ks < 4; ++ks) {
            const float p = __expf(sc[mi][ks][r] - mnew);
            sc[mi][ks][r] = p;
            rs += p;
          }
          for (int off = 1; off < 16; off <<= 1) rs += __shfl_xor(rs, off);
          l_i[mi][r] = l_i[mi][r] * alpha + rs;
          for (int u = 0; u < 4; ++u) o_acc[mi][u][r] *= alpha;
        }

      // ---- P: C-layout -> A-layout via swizzled per-wave LDS slab ----
      for (int mi = 0; mi < 2; ++mi)
        for (int r = 0; r < 4; ++r) {
          const int ql = mi * 16 + g * 4 + r;
          const int sw = ((ql >> 2) & 3) * 8;
          for (int ks = 0; ks < 4; ++ks) {
            const int kk = ks * 16 + c;
            ps[ql * 72 + (kk ^ sw)] = f2b(sc[mi][ks][r]);
          }
        }
      short8 ap[2][2];
      for (int mi = 0; mi < 2; ++mi) {
        const int ql = mi * 16 + c;
        const int sw = ((ql >> 2) & 3) * 8;
        for (int kc = 0; kc < 2; ++kc) {
          const int kk = kc * 32 + g * 8;
          ap[mi][kc] = *(const short8*)(ps + ql * 72 + (kk ^ sw));
        }
      }

      // ---- O += P V (V^T frags from LDS; 16 MFMA) ----
      for (int u = 0; u < 4; ++u)
        for (int kc = 0; kc < 2; ++kc) {
          const short8 bv = *(const short8*)(Vs + (u * 16 + c) * 72 + kc * 32 + g * 8);
          for (int mi = 0; mi < 2; ++mi)
            o_acc[mi][u] = __builtin_amdgcn_mfma_f32_16x16x32_bf16(ap[mi][kc], bv, o_acc[mi][u], 0, 0, 0);
        }
    }

    // ---- normalize + merge heads ----
    for (int mi = 0; mi < 2; ++mi)
      for (int r = 0; r < 4; ++r) {
        const float inv = 1.0f / l_i[mi][r];
        const int srow = qbase + mi * 16 + g * 4 + r;
        float* orow = out + ((size_t)(b * S_LEN + srow)) * D_MODEL + h * DH;
        for (int u = 0; u < 4; ++u)
          orow[u * 16 + c] = o_acc[mi][u][r] * inv;
      }
  }
}

// ---------------------------------------------------------------------------
extern "C" void kernel_launch(void* const* d_in, const int* in_sizes, int n_in,
                              void* d_out, int out_size, void* d_ws, size_t ws_size,
                              hipStream_t stream) {
  const float* X    = (const float*)d_in[0];   // [4,2048,1024]
  const float* mask = (const float*)d_in[1];   // [4,2048]
  const float* W    = (const float*)d_in[2];   // [1024,3072]
  const float* bias = (const float*)d_in[3];   // [3072]

  float* out   = (float*)d_out;                         // attn_output [4,2048,1024]
  float* presK = out + (size_t)M_TOT * D_MODEL;         // present[0]  [4,16,2048,64]
  float* presV = presK + (size_t)M_TOT * D_MODEL;       // present[1]

  char* ws = (char*)d_ws;
  unsigned short* Xb = (unsigned short*)(ws);                    // 16 MB  X bf16 [8192,1024]
  unsigned short* Wt = (unsigned short*)(ws + 16777216);         //  6 MB  W^T bf16 [3072,1024]
  unsigned short* Qb = (unsigned short*)(ws + 23068672);         // 16 MB  Q bf16 [bh,2048,64]
  unsigned short* Kb = (unsigned short*)(ws + 39845888);         // 16 MB  K bf16 [bh,2048,64]
  unsigned short* Vb = (unsigned short*)(ws + 56623104);         // 16 MB  V bf16 [bh,2048,64]

  k_convert_x<<<dim3(8192), dim3(256), 0, stream>>>(X, Xb);
  k_wt<<<dim3(96, 32), dim3(32, 8), 0, stream>>>(W, Wt);
  k_gemm_qkv<<<dim3(24, 64), dim3(256), 0, stream>>>(Xb, Wt, bias, Qb, Kb, Vb, presK, presV);
  k_flash<<<dim3(8, 64), dim3(256), 0, stream>>>(Qb, Kb, Vb, mask, out);
}

// Round 4
// 337.597 us; speedup vs baseline: 1.6403x; 1.0853x over previous
//
#include <hip/hip_runtime.h>
#include <stdint.h>

// ---------------------------------------------------------------------------
// GPT-2 attention block: qkv = X@W + b; causal MHA; outputs attn_out + present
// B=4 S=2048 D=1024 H=16 Dh=64.  bf16 MFMA path.
// R4: flash staging via global_load_lds with XOR swizzle folded into the
//     GLOBAL gather address (LDS side is rigid base+lane*16; global side is
//     per-lane) -> zero staging VALU, zero ds_write conflicts. V transposed
//     once in global (k_vt) instead of per-tile in LDS (was 8-way conflicts).
//     8 waves x 16 q-rows per block -> 16 waves/CU (was 8).
// ---------------------------------------------------------------------------

#define B_SZ    4
#define S_LEN   2048
#define D_MODEL 1024
#define N3      3072
#define H_NUM   16
#define DH      64
#define M_TOT   8192   // B*S

typedef __attribute__((ext_vector_type(8))) short short8;   // 8 bf16 (4 VGPRs)
typedef __attribute__((ext_vector_type(4))) float f32x4;    // MFMA C/D

__device__ __forceinline__ unsigned short f2b(float f) {
  union { float f; unsigned int u; } x;
  x.f = f;
  unsigned int u = x.u;
  u += 0x7fffu + ((u >> 16) & 1u);   // round-to-nearest-even
  return (unsigned short)(u >> 16);
}

// async global->LDS, 16B per lane. LDS dest = wave-uniform base + lane*16.
__device__ __forceinline__ void async16(const void* g, void* l) {
  __builtin_amdgcn_global_load_lds((const __attribute__((address_space(1))) void*)g,
                                   (__attribute__((address_space(3))) void*)l,
                                   16, 0, 0);
}

// ---------------- kernel 1: hidden_states fp32 -> bf16 ---------------------
__global__ void k_convert_x(const float* __restrict__ X, unsigned short* __restrict__ Xb) {
  const int i = (blockIdx.x * 256 + threadIdx.x) * 4;
  const float4 v = *(const float4*)(X + i);
  ushort4 o;
  o.x = f2b(v.x); o.y = f2b(v.y); o.z = f2b(v.z); o.w = f2b(v.w);
  *(ushort4*)(Xb + i) = o;
}

// ---------------- kernel 2: W [D,3D] fp32 -> W^T [3D,D] bf16 ----------------
__global__ void k_wt(const float* __restrict__ W, unsigned short* __restrict__ Wt) {
  __shared__ float tile[32][33];
  const int n0 = blockIdx.x * 32, k0 = blockIdx.y * 32;
  const int tx = threadIdx.x, ty = threadIdx.y;   // 32 x 8
  for (int i = 0; i < 32; i += 8)
    tile[ty + i][tx] = W[(size_t)(k0 + ty + i) * N3 + n0 + tx];
  __syncthreads();
  for (int i = 0; i < 32; i += 8)
    Wt[(size_t)(n0 + ty + i) * D_MODEL + k0 + tx] = f2b(tile[tx][ty + i]);
}

// ---------------- kernel 3: QKV GEMM (128x128 tile, BK=32) ------------------
__global__ __launch_bounds__(256) void k_gemm_qkv(
    const unsigned short* __restrict__ Xb, const unsigned short* __restrict__ Wt,
    const float* __restrict__ bias,
    unsigned short* __restrict__ Qb, unsigned short* __restrict__ Kb,
    float* __restrict__ presK, float* __restrict__ presV) {
  __shared__ __align__(16) unsigned short As[128 * 32];
  __shared__ __align__(16) unsigned short Bs[128 * 32];
  const int t = threadIdx.x;
  const int lane = t & 63, wave = t >> 6;
  const int g = lane >> 4, c = lane & 15;
  const int m0 = blockIdx.y * 128, n0 = blockIdx.x * 128;
  const int wm = (wave >> 1) * 64, wn = (wave & 1) * 64;

  const f32x4 zero = {0.f, 0.f, 0.f, 0.f};
  f32x4 acc[4][4];
  for (int i = 0; i < 4; ++i)
    for (int j = 0; j < 4; ++j) acc[i][j] = zero;

  const int row_a = t >> 2;          // 0..63
  const int col_a = (t & 3) * 8;     // bf16 elems
  const unsigned short* gA = Xb + (size_t)(m0 + row_a) * D_MODEL + col_a;
  const unsigned short* gB = Wt + (size_t)(n0 + row_a) * D_MODEL + col_a;
  const int wbase = wave * 1024;     // wave-uniform LDS byte base

  for (int k0 = 0; k0 < D_MODEL; k0 += 32) {
    __syncthreads();
    async16(gA + k0,                (char*)As + wbase);
    async16(gA + k0 + 64 * D_MODEL, (char*)As + 4096 + wbase);
    async16(gB + k0,                (char*)Bs + wbase);
    async16(gB + k0 + 64 * D_MODEL, (char*)Bs + 4096 + wbase);
    __syncthreads();

    short8 af[4], bf[4];
    for (int mi = 0; mi < 4; ++mi)
      af[mi] = *(const short8*)(As + (wm + mi * 16 + c) * 32 + g * 8);
    for (int ni = 0; ni < 4; ++ni)
      bf[ni] = *(const short8*)(Bs + (wn + ni * 16 + c) * 32 + g * 8);
    for (int mi = 0; mi < 4; ++mi)
      for (int ni = 0; ni < 4; ++ni)
        acc[mi][ni] = __builtin_amdgcn_mfma_f32_16x16x32_bf16(af[mi], bf[ni], acc[mi][ni], 0, 0, 0);
  }

  // epilogue: bias + scatter.  C/D layout: col=lane&15, row=(lane>>4)*4+reg.
  for (int ni = 0; ni < 4; ++ni) {
    const int n = n0 + wn + ni * 16 + c;
    const float bv = bias[n];
    const int sec = n >> 10;            // 0=q 1=k 2=v
    const int d = n & 1023;
    const int h = d >> 6, dh = d & 63;
    for (int mi = 0; mi < 4; ++mi) {
      for (int r = 0; r < 4; ++r) {
        const int m = m0 + wm + mi * 16 + g * 4 + r;
        const int b = m >> 11, s = m & 2047;
        const float val = acc[mi][ni][r] + bv;
        const size_t hidx = ((size_t)((b * H_NUM + h) * S_LEN + s)) * DH + dh;
        if (sec == 0) {
          Qb[hidx] = f2b(val);
        } else if (sec == 1) {
          presK[hidx] = val;
          Kb[hidx] = f2b(val);
        } else {
          presV[hidx] = val;
        }
      }
    }
  }
}

// ---------------- kernel 3b: presV fp32 [bh,s,dh] -> Vt bf16 [bh,dh,s] ------
__global__ __launch_bounds__(256) void k_vt(const float* __restrict__ presV,
                                            unsigned short* __restrict__ Vt) {
  __shared__ unsigned short tile[64 * 72];
  const int t = threadIdx.x;
  const int bh = blockIdx.y;
  const int s0 = blockIdx.x * 64;
  const int row = t >> 2;            // s-row 0..63
  const int dh0 = (t & 3) * 16;
  const float* src = presV + ((size_t)bh * S_LEN + s0 + row) * DH + dh0;
  for (int i = 0; i < 4; ++i) {
    const float4 v = *(const float4*)(src + i * 4);
    const int dh = dh0 + i * 4;
    tile[(dh + 0) * 72 + row] = f2b(v.x);
    tile[(dh + 1) * 72 + row] = f2b(v.y);
    tile[(dh + 2) * 72 + row] = f2b(v.z);
    tile[(dh + 3) * 72 + row] = f2b(v.w);
  }
  __syncthreads();
  const int dh = t >> 2, sc0 = (t & 3) * 16;
  unsigned short* dst = Vt + ((size_t)bh * DH + dh) * S_LEN + s0 + sc0;
  short8 o0, o1;
  for (int i = 0; i < 8; ++i) {
    o0[i] = (short)tile[dh * 72 + sc0 + i];
    o1[i] = (short)tile[dh * 72 + sc0 + 8 + i];
  }
  *(short8*)(dst) = o0;
  *(short8*)(dst + 8) = o1;
}

// ---------------- kernel 4: causal flash attention --------------------------
// grid (8, 64 bh); 512 thr = 8 waves x 16 q-rows; q-tile pair (x, 15-x).
// K/V^T tiles staged by global_load_lds with XOR swizzle in the GLOBAL address:
// LDS [row][slot] where slot holds global chunk (slot ^ (row&7)) -> frag reads
// at slot=(kc*4+g)^(c&7) are conflict-free (2 lanes/bank), staging is VALU-free.
__global__ __launch_bounds__(512) void k_flash(
    const unsigned short* __restrict__ Qb, const unsigned short* __restrict__ Kb,
    const unsigned short* __restrict__ Vt, const float* __restrict__ mask,
    float* __restrict__ out) {
  __shared__ __align__(16) unsigned short Ks[64 * 64];     // [krow][slot] swizzled
  __shared__ __align__(16) unsigned short Vs[64 * 64];     // [dh][slot]  swizzled
  __shared__ __align__(16) unsigned short Ps[8][16 * 72];  // per-wave P slab
  const int t = threadIdx.x;
  const int lane = t & 63, wave = t >> 6;
  const int g = lane >> 4, c = lane & 15;
  const int bh = blockIdx.y;
  const int b = bh >> 4, h = bh & 15;
  // staging: thread -> (row 0..63, swizzled 16B chunk)
  const int srow = t >> 3;
  const int schunk = (t & 7) ^ (srow & 7);
  const unsigned short* gK0 = Kb + ((size_t)bh * S_LEN + srow) * DH + schunk * 8;
  const unsigned short* gV0 = Vt + ((size_t)bh * DH + srow) * S_LEN + schunk * 8;
  char* ldsK = (char*)Ks + wave * 1024;    // wave-uniform LDS dest
  char* ldsV = (char*)Vs + wave * 1024;
  unsigned short* ps = &Ps[wave][0];
  const int sw_w = g * 8;                  // P write swizzle (ql>>2 == g)
  const int sw_r = (c >> 2) * 8;           // P read swizzle  (ql' == c)
  const int kslot = (c & 7);               // frag-read slot xor term

  for (int phase = 0; phase < 2; ++phase) {
    const int x = phase ? 15 - (int)blockIdx.x : (int)blockIdx.x;
    const int qb = x * 128;
    const int qw = qb + wave * 16;         // this wave's 16 q rows

    // Q frags (A-layout: m=c, k=g*8+j per 32-wide chunk)
    short8 aq[2];
    const size_t qoff = ((size_t)bh * S_LEN + qw) * DH;
    for (int kc = 0; kc < 2; ++kc)
      aq[kc] = *(const short8*)(Qb + qoff + (size_t)c * DH + kc * 32 + g * 8);

    const f32x4 zero = {0.f, 0.f, 0.f, 0.f};
    float m_i[4], l_i[4];
    f32x4 o_acc[4];
    for (int r = 0; r < 4; ++r) { m_i[r] = -1e30f; l_i[r] = 0.f; }
    for (int u = 0; u < 4; ++u) o_acc[u] = zero;

    for (int kb = 0; kb < qb + 128; kb += 64) {
      __syncthreads();                      // prev iter LDS reads done
      async16(gK0 + (size_t)kb * DH, ldsK); // stage K tile (1KB/wave)
      async16(gV0 + kb, ldsV);              // stage V^T tile
      __syncthreads();                      // vmcnt drained before barrier

      // ---- S = Q K^T (8 MFMA) ----
      f32x4 sc[4];
      for (int ks = 0; ks < 4; ++ks) sc[ks] = zero;
      for (int ks = 0; ks < 4; ++ks) {
        const int krow = ks * 16 + c;
        for (int kc = 0; kc < 2; ++kc) {
          const short8 bk = *(const short8*)(Ks + krow * 64 + (((kc * 4 + g) ^ kslot) * 8));
          sc[ks] = __builtin_amdgcn_mfma_f32_16x16x32_bf16(aq[kc], bk, sc[ks], 0, 0, 0);
        }
      }

      // ---- scale, causal, attention_mask ----
      float am[4];
      for (int ks = 0; ks < 4; ++ks)
        am[ks] = (1.0f - mask[b * S_LEN + kb + ks * 16 + c]) * -10000.0f;
      for (int r = 0; r < 4; ++r) {
        const int qrow = qw + g * 4 + r;
        for (int ks = 0; ks < 4; ++ks) {
          const int kcol = kb + ks * 16 + c;
          float v = sc[ks][r] * 0.125f;          // 1/sqrt(64)
          if (kcol > qrow) v = -10000.0f;        // causal (ref semantics)
          sc[ks][r] = v + am[ks];
        }
      }

      // ---- online softmax (row = 16 lanes sharing g) ----
      for (int r = 0; r < 4; ++r) {
        float mx = fmaxf(fmaxf(sc[0][r], sc[1][r]), fmaxf(sc[2][r], sc[3][r]));
        for (int off = 1; off < 16; off <<= 1) mx = fmaxf(mx, __shfl_xor(mx, off));
        const float mnew = fmaxf(m_i[r], mx);
        const float alpha = __expf(m_i[r] - mnew);
        m_i[r] = mnew;
        float rs = 0.f;
        for (int ks = 0; ks < 4; ++ks) {
          const float p = __expf(sc[ks][r] - mnew);
          sc[ks][r] = p;
          rs += p;
        }
        for (int off = 1; off < 16; off <<= 1) rs += __shfl_xor(rs, off);
        l_i[r] = l_i[r] * alpha + rs;
        for (int u = 0; u < 4; ++u) o_acc[u][r] *= alpha;
      }

      // ---- P: C-layout -> A-layout via swizzled per-wave LDS slab ----
      for (int r = 0; r < 4; ++r) {
        const int ql = g * 4 + r;
        for (int ks = 0; ks < 4; ++ks)
          ps[ql * 72 + ((ks * 16 + c) ^ sw_w)] = f2b(sc[ks][r]);
      }
      short8 ap[2];
      for (int kc = 0; kc < 2; ++kc)
        ap[kc] = *(const short8*)(ps + c * 72 + ((kc * 32 + g * 8) ^ sw_r));

      // ---- O += P V (8 MFMA, V^T frags from swizzled LDS) ----
      for (int u = 0; u < 4; ++u) {
        const int vrow = u * 16 + c;
        for (int kc = 0; kc < 2; ++kc) {
          const short8 bv = *(const short8*)(Vs + vrow * 64 + (((kc * 4 + g) ^ kslot) * 8));
          o_acc[u] = __builtin_amdgcn_mfma_f32_16x16x32_bf16(ap[kc], bv, o_acc[u], 0, 0, 0);
        }
      }
    }

    // ---- normalize + merge heads ----
    for (int r = 0; r < 4; ++r) {
      const float inv = 1.0f / l_i[r];
      const int srow_o = qw + g * 4 + r;
      float* orow = out + ((size_t)(b * S_LEN + srow_o)) * D_MODEL + h * DH;
      for (int u = 0; u < 4; ++u)
        orow[u * 16 + c] = o_acc[u][r] * inv;
    }
  }
}

// ---------------------------------------------------------------------------
extern "C" void kernel_launch(void* const* d_in, const int* in_sizes, int n_in,
                              void* d_out, int out_size, void* d_ws, size_t ws_size,
                              hipStream_t stream) {
  const float* X    = (const float*)d_in[0];   // [4,2048,1024]
  const float* mask = (const float*)d_in[1];   // [4,2048]
  const float* W    = (const float*)d_in[2];   // [1024,3072]
  const float* bias = (const float*)d_in[3];   // [3072]

  float* out   = (float*)d_out;                         // attn_output [4,2048,1024]
  float* presK = out + (size_t)M_TOT * D_MODEL;         // present[0]  [4,16,2048,64]
  float* presV = presK + (size_t)M_TOT * D_MODEL;       // present[1]

  char* ws = (char*)d_ws;
  unsigned short* Xb = (unsigned short*)(ws);                    // 16 MB  X bf16 [8192,1024]
  unsigned short* Wt = (unsigned short*)(ws + 16777216);         //  6 MB  W^T bf16 [3072,1024]
  unsigned short* Qb = (unsigned short*)(ws + 23068672);         // 16 MB  Q bf16 [bh,2048,64]
  unsigned short* Kb = (unsigned short*)(ws + 39845888);         // 16 MB  K bf16 [bh,2048,64]
  unsigned short* Vt = (unsigned short*)(ws + 56623104);         // 16 MB  V^T bf16 [bh,64,2048]

  k_convert_x<<<dim3(8192), dim3(256), 0, stream>>>(X, Xb);
  k_wt<<<dim3(96, 32), dim3(32, 8), 0, stream>>>(W, Wt);
  k_gemm_qkv<<<dim3(24, 64), dim3(256), 0, stream>>>(Xb, Wt, bias, Qb, Kb, presK, presV);
  k_vt<<<dim3(32, 64), dim3(256), 0, stream>>>(presV, Vt);
  k_flash<<<dim3(8, 64), dim3(512), 0, stream>>>(Qb, Kb, Vt, mask, out);
}